// Round 3
// baseline (354.981 us; speedup 1.0000x reference)
//
#include <hip/hip_runtime.h>
#include <hip/hip_bf16.h>

typedef __bf16 bf16_t;
typedef __bf16 bf16x8_t __attribute__((ext_vector_type(8)));
typedef float f32x4_t __attribute__((ext_vector_type(4)));

#define NEG_BIG -1000000000.0f

// async global->LDS, 16B per lane; LDS dest = wave-uniform base + lane*16
__device__ __forceinline__ void gld_lds16(const void* g, void* l) {
    __builtin_amdgcn_global_load_lds((const __attribute__((address_space(1))) void*)g,
                                     (__attribute__((address_space(3))) void*)l,
                                     16, 0, 0);
}

__device__ __forceinline__ float tanh_fast(float x) {
    float e = __expf(2.0f * x);
    return 1.0f - 2.0f / (e + 1.0f);
}

// ---------------------------------------------------------------------------
// K0 (fused prep): blocks [0,16384): enc f32 -> bf16 (33.5M elems)
//                  blocks [16384,16896): W_enc f32 -> bf16 (1M elems)
//                  blocks [16896,17920): bias[b][a] = dec·W_dec[a] + W_b[a]
//                  blocks [17920,17952): zero scores (atomic accumulator)
__global__ void k_prep(const float* __restrict__ enc, const float* __restrict__ Ww,
                       const float* __restrict__ dec, const float* __restrict__ Wb,
                       bf16_t* __restrict__ encb, bf16_t* __restrict__ Bw,
                       float* __restrict__ bias, float* __restrict__ score) {
    const int bi = blockIdx.x;
    const int t = threadIdx.x;
    if (bi < 16384) {
        size_t flat = (size_t)bi * 2048 + t * 8;
        float4 f0 = *(const float4*)(enc + flat);
        float4 f1 = *(const float4*)(enc + flat + 4);
        bf16x8_t v;
        v[0] = (bf16_t)f0.x; v[1] = (bf16_t)f0.y; v[2] = (bf16_t)f0.z; v[3] = (bf16_t)f0.w;
        v[4] = (bf16_t)f1.x; v[5] = (bf16_t)f1.y; v[6] = (bf16_t)f1.z; v[7] = (bf16_t)f1.w;
        *(bf16x8_t*)(encb + flat) = v;
    } else if (bi < 16896) {
        size_t flat = (size_t)(bi - 16384) * 2048 + t * 8;   // over 1M W_enc elems
        int a = (int)(flat >> 10), e = (int)(flat & 1023);
        const float* src = Ww + (size_t)a * 2048 + 1024 + e;
        float4 f0 = *(const float4*)src;
        float4 f1 = *(const float4*)(src + 4);
        bf16x8_t v;
        v[0] = (bf16_t)f0.x; v[1] = (bf16_t)f0.y; v[2] = (bf16_t)f0.z; v[3] = (bf16_t)f0.w;
        v[4] = (bf16_t)f1.x; v[5] = (bf16_t)f1.y; v[6] = (bf16_t)f1.z; v[7] = (bf16_t)f1.w;
        *(bf16x8_t*)(Bw + flat) = v;
    } else if (bi < 17920) {
        __shared__ float wrow[1024];
        int a = bi - 16896;
        *(float4*)(wrow + t * 4) = *(const float4*)(Ww + (size_t)a * 2048 + t * 4);
        __syncthreads();
        int b = t >> 3, j = t & 7;                // 32 batches x 8 threads
        const float* dp = dec + b * 1024 + j * 128;
        const float* wp = wrow + j * 128;
        float s = 0.0f;
#pragma unroll 8
        for (int i = 0; i < 128; i += 4) {
            float4 dv = *(const float4*)(dp + i);
            float4 wv = *(const float4*)(wp + i);
            s += dv.x * wv.x + dv.y * wv.y + dv.z * wv.z + dv.w * wv.w;
        }
        s += __shfl_xor(s, 1);
        s += __shfl_xor(s, 2);
        s += __shfl_xor(s, 4);
        if (j == 0) bias[b * 1024 + a] = s + Wb[a];
    } else {
        float4 z = {0.f, 0.f, 0.f, 0.f};
        *(float4*)(score + (size_t)(bi - 17920) * 1024 + t * 4) = z;
    }
}

// ---------------------------------------------------------------------------
// K1: enc_proj GEMM (bf16 MFMA, both operands via global_load_lds)
//     + fused tanh + v-dot -> atomicAdd scores[m]
// tile 128x128, BK=64 (16 K-iters, 32 MFMA per barrier pair), 4 waves 2x2.
// grid (bm=256 FAST, bn=8): blocks sharing an A-tile == bm (mod 8) -> same XCD.
// LDS rows are 128 B; 16B-unit u at row r holds global unit u^(r&7); fragment
// reads are 2-way bank-aliased per 16-lane quarter (free, m136).
__global__ __launch_bounds__(256) void k_gemm_score(
    const bf16_t* __restrict__ A, const bf16_t* __restrict__ Bw,
    const float* __restrict__ bias, const float* __restrict__ v,
    float* __restrict__ scores) {
    __shared__ __attribute__((aligned(16))) bf16_t As[128 * 64];
    __shared__ __attribute__((aligned(16))) bf16_t Bs[128 * 64];

    const int tid = threadIdx.x;
    const int lane = tid & 63;
    const int wid = tid >> 6;
    const int wm = wid >> 1, wn = wid & 1;
    const int bm = blockIdx.x;   // 0..255 (M tiles) -- FAST dim for XCD affinity
    const int bn = blockIdx.y;   // 0..7   (N tiles)
    const int rsel = lane & 15, kg = lane >> 4;

    f32x4_t acc[4][4] = {};

    // staging: wave wid stages chunks c = wid*4..wid*4+3 (each = 8 rows x 128 B)
    const int c0 = wid * 4;
    const int rr = lane >> 3;              // row within chunk (0..7)
    const int ju = (lane & 7) ^ rr;        // swizzled source 16B-unit
    const bf16_t* asrc = A  + (size_t)(bm * 128 + c0 * 8 + rr) * 1024 + ju * 8;
    const bf16_t* bsrc = Bw + (size_t)(bn * 128 + c0 * 8 + rr) * 1024 + ju * 8;

    for (int kt = 0; kt < 16; ++kt) {
        const int k0 = kt * 64;
#pragma unroll
        for (int c = 0; c < 4; ++c) {
            gld_lds16(asrc + (size_t)c * 8 * 1024 + k0, As + (c0 + c) * 512);
            gld_lds16(bsrc + (size_t)c * 8 * 1024 + k0, Bs + (c0 + c) * 512);
        }
        __syncthreads();
#pragma unroll
        for (int s = 0; s < 2; ++s) {
            bf16x8_t af[4], bf[4];
#pragma unroll
            for (int fm = 0; fm < 4; ++fm) {
                int row = wm * 64 + fm * 16 + rsel;
                af[fm] = *(const bf16x8_t*)(As + row * 64 + (((s * 4 + kg) ^ (row & 7)) * 8));
            }
#pragma unroll
            for (int fn = 0; fn < 4; ++fn) {
                int row = wn * 64 + fn * 16 + rsel;
                bf[fn] = *(const bf16x8_t*)(Bs + row * 64 + (((s * 4 + kg) ^ (row & 7)) * 8));
            }
#pragma unroll
            for (int fm = 0; fm < 4; ++fm)
#pragma unroll
                for (int fn = 0; fn < 4; ++fn)
                    acc[fm][fn] = __builtin_amdgcn_mfma_f32_16x16x32_bf16(af[fm], bf[fn], acc[fm][fn], 0, 0, 0);
        }
        __syncthreads();
    }

    // epilogue: energy = tanh(acc + bias[b][a]); scores[m] += energy * v[a]
    // C/D layout (m89-verified): row(M) = kg*4 + reg, col(N=a) = rsel
    const int b = bm >> 3;   // 128-row M-tiles lie within one batch
    float bias_l[4], v_l[4];
#pragma unroll
    for (int fn = 0; fn < 4; ++fn) {
        int a = bn * 128 + wn * 64 + fn * 16 + rsel;
        bias_l[fn] = bias[b * 1024 + a];
        v_l[fn] = v[a];
    }
    float part[16];
#pragma unroll
    for (int fm = 0; fm < 4; ++fm)
#pragma unroll
        for (int r = 0; r < 4; ++r) {
            float p = 0.0f;
#pragma unroll
            for (int fn = 0; fn < 4; ++fn) {
                float x = acc[fm][fn][r] + bias_l[fn];
                p += tanh_fast(x) * v_l[fn];
            }
            part[fm * 4 + r] = p;
        }
#pragma unroll
    for (int k = 0; k < 16; ++k) {
        part[k] += __shfl_xor(part[k], 1);
        part[k] += __shfl_xor(part[k], 2);
        part[k] += __shfl_xor(part[k], 4);
        part[k] += __shfl_xor(part[k], 8);
    }
    const int mrow0 = bm * 128 + wm * 64 + kg * 4;
#pragma unroll
    for (int k = 0; k < 16; ++k) {
        if (rsel == k) {
            int fm = k >> 2, r = k & 3;
            atomicAdd(&scores[mrow0 + fm * 16 + r], part[k]);
        }
    }
}

// ---------------------------------------------------------------------------
// K2: masked softmax over Tx per batch row
__global__ void k_softmax(const float* __restrict__ scores, const int* __restrict__ mask,
                          float* __restrict__ alpha) {
    __shared__ float red[4];
    __shared__ float red2[4];
    int b = blockIdx.x, t = threadIdx.x;
    float4 s = *(const float4*)(scores + b * 1024 + t * 4);
    int4 m = *(const int4*)(mask + b * 1024 + t * 4);
    float v0 = m.x ? s.x : NEG_BIG;
    float v1 = m.y ? s.y : NEG_BIG;
    float v2 = m.z ? s.z : NEG_BIG;
    float v3 = m.w ? s.w : NEG_BIG;
    float mx = fmaxf(fmaxf(v0, v1), fmaxf(v2, v3));
#pragma unroll
    for (int o = 1; o < 64; o <<= 1) mx = fmaxf(mx, __shfl_xor(mx, o));
    if ((t & 63) == 0) red[t >> 6] = mx;
    __syncthreads();
    mx = fmaxf(fmaxf(red[0], red[1]), fmaxf(red[2], red[3]));
    float e0 = m.x ? __expf(v0 - mx) : 0.0f;
    float e1 = m.y ? __expf(v1 - mx) : 0.0f;
    float e2 = m.z ? __expf(v2 - mx) : 0.0f;
    float e3 = m.w ? __expf(v3 - mx) : 0.0f;
    float sum = e0 + e1 + e2 + e3;
#pragma unroll
    for (int o = 1; o < 64; o <<= 1) sum += __shfl_xor(sum, o);
    if ((t & 63) == 0) red2[t >> 6] = sum;
    __syncthreads();
    float inv = 1.0f / (red2[0] + red2[1] + red2[2] + red2[3]);
    float4 out = {e0 * inv, e1 * inv, e2 * inv, e3 * inv};
    *(float4*)(alpha + b * 1024 + t * 4) = out;
}

// ---------------------------------------------------------------------------
// K3: context partials from bf16 encb -- no atomics; part[chunk*2+j][b][e]
__global__ void k_ctx_part(const bf16_t* __restrict__ encb, const float* __restrict__ alpha,
                           float* __restrict__ part) {
    int chunk = blockIdx.x;  // 0..31 (t-chunks of 32)
    int b = blockIdx.y;      // 0..31
    int t = threadIdx.x;
    int j = t >> 7;          // 0/1: row interleave
    int e = (t & 127) * 8;
    const float* ap = alpha + b * 1024 + chunk * 32;
    const bf16_t* ep = encb + ((size_t)b * 1024 + chunk * 32) * 1024 + e;
    float acc[8] = {};
    for (int i = j; i < 32; i += 2) {
        float a = ap[i];
        bf16x8_t x = *(const bf16x8_t*)(ep + (size_t)i * 1024);
#pragma unroll
        for (int q = 0; q < 8; ++q) acc[q] += a * (float)x[q];
    }
    float4 o0 = {acc[0], acc[1], acc[2], acc[3]};
    float4 o1 = {acc[4], acc[5], acc[6], acc[7]};
    float* dst = part + ((size_t)(chunk * 2 + j) * 32 + b) * 1024 + e;
    *(float4*)dst = o0;
    *(float4*)(dst + 4) = o1;
}

// K4: context[b][e] = sum over 64 partial chunks
__global__ void k_ctx_reduce(const float* __restrict__ part, float* __restrict__ ctx) {
    int b = blockIdx.x, t = threadIdx.x;
    int e = t * 4;
    float ax = 0.f, ay = 0.f, az = 0.f, aw = 0.f;
#pragma unroll 8
    for (int c = 0; c < 64; ++c) {
        float4 x = *(const float4*)(part + ((size_t)c * 32 + b) * 1024 + e);
        ax += x.x; ay += x.y; az += x.z; aw += x.w;
    }
    float4 o = {ax, ay, az, aw};
    *(float4*)(ctx + b * 1024 + e) = o;
}

// ---------------------------------------------------------------------------
extern "C" void kernel_launch(void* const* d_in, const int* in_sizes, int n_in,
                              void* d_out, int out_size, void* d_ws, size_t ws_size,
                              hipStream_t stream) {
    const float* dec  = (const float*)d_in[0];   // [32][1024]
    const float* enc  = (const float*)d_in[1];   // [32][1024][1024]
    const int*   mask = (const int*)d_in[2];     // [32][1024]
    const float* Ww   = (const float*)d_in[3];   // [1024][2048]
    const float* Wb   = (const float*)d_in[4];   // [1024]
    const float* vw   = (const float*)d_in[5];   // [1024]
    float* out = (float*)d_out;                  // [0:32768] context, [32768:65536] alpha

    char* ws = (char*)d_ws;
    bf16_t* encb  = (bf16_t*)ws;                          // 67,108,864 B
    bf16_t* Bw    = (bf16_t*)(ws + 67108864);             //  2,097,152 B
    float*  bias  = (float*)(ws + 69206016);              //    131,072 B
    float*  score = (float*)(ws + 69337088);              //    131,072 B
    float*  part  = (float*)(ws + 69468160);              //  8,388,608 B (total ~74.3 MB)

    k_prep<<<17952, 256, 0, stream>>>(enc, Ww, dec, Wb, encb, Bw, bias, score);
    k_gemm_score<<<dim3(256, 8), 256, 0, stream>>>(encb, Bw, bias, vw, score);
    k_softmax<<<32, 256, 0, stream>>>(score, mask, out + 32768);
    k_ctx_part<<<dim3(32, 32), 256, 0, stream>>>(encb, out + 32768, part);
    k_ctx_reduce<<<32, 256, 0, stream>>>(part, out);
}

// Round 4
// 349.596 us; speedup vs baseline: 1.0154x; 1.0154x over previous
//
#include <hip/hip_runtime.h>
#include <hip/hip_bf16.h>

typedef __bf16 bf16_t;
typedef __bf16 bf16x8_t __attribute__((ext_vector_type(8)));
typedef float f32x4_t __attribute__((ext_vector_type(4)));

#define NEG_BIG -1000000000.0f

// async global->LDS, 16B per lane; LDS dest = wave-uniform base + lane*16
__device__ __forceinline__ void gld_lds16(const void* g, void* l) {
    __builtin_amdgcn_global_load_lds((const __attribute__((address_space(1))) void*)g,
                                     (__attribute__((address_space(3))) void*)l,
                                     16, 0, 0);
}

__device__ __forceinline__ float tanh_fast(float x) {
    float e = __expf(2.0f * x);
    return 1.0f - 2.0f / (e + 1.0f);
}

// ---------------------------------------------------------------------------
// K0 (prep-lite): blocks [0,512):    W_enc f32 -> bf16 (1M elems)
//                 blocks [512,1536): bias[b][a] = dec·W_dec[a] + W_b[a]
//                 blocks [1536,1568): zero scores (atomic accumulator)
__global__ void k_prep(const float* __restrict__ Ww, const float* __restrict__ dec,
                       const float* __restrict__ Wb, bf16_t* __restrict__ Bw,
                       float* __restrict__ bias, float* __restrict__ score) {
    const int bi = blockIdx.x;
    const int t = threadIdx.x;
    if (bi < 512) {
        size_t flat = (size_t)bi * 2048 + t * 8;   // over 1M W_enc elems
        int a = (int)(flat >> 10), e = (int)(flat & 1023);
        const float* src = Ww + (size_t)a * 2048 + 1024 + e;
        float4 f0 = *(const float4*)src;
        float4 f1 = *(const float4*)(src + 4);
        bf16x8_t v;
        v[0] = (bf16_t)f0.x; v[1] = (bf16_t)f0.y; v[2] = (bf16_t)f0.z; v[3] = (bf16_t)f0.w;
        v[4] = (bf16_t)f1.x; v[5] = (bf16_t)f1.y; v[6] = (bf16_t)f1.z; v[7] = (bf16_t)f1.w;
        *(bf16x8_t*)(Bw + flat) = v;
    } else if (bi < 1536) {
        __shared__ float wrow[1024];
        int a = bi - 512;
        *(float4*)(wrow + t * 4) = *(const float4*)(Ww + (size_t)a * 2048 + t * 4);
        __syncthreads();
        int b = t >> 3, j = t & 7;                // 32 batches x 8 threads
        const float* dp = dec + b * 1024 + j * 128;
        const float* wp = wrow + j * 128;
        float s = 0.0f;
#pragma unroll 8
        for (int i = 0; i < 128; i += 4) {
            float4 dv = *(const float4*)(dp + i);
            float4 wv = *(const float4*)(wp + i);
            s += dv.x * wv.x + dv.y * wv.y + dv.z * wv.z + dv.w * wv.w;
        }
        s += __shfl_xor(s, 1);
        s += __shfl_xor(s, 2);
        s += __shfl_xor(s, 4);
        if (j == 0) bias[b * 1024 + a] = s + Wb[a];
    } else {
        float4 z = {0.f, 0.f, 0.f, 0.f};
        *(float4*)(score + (size_t)(bi - 1536) * 1024 + t * 4) = z;
    }
}

// ---------------------------------------------------------------------------
// K1: enc_proj GEMM (bf16 MFMA; A = f32 enc converted in-register during
//     staging, B = bf16 W_enc via global_load_lds) + fused tanh + v-dot
//     -> atomicAdd scores[m]
// tile 128x128, BK=32, 256 threads = 4 waves (2x2), wave tile 64x64
// grid (bm=256 FAST, bn=8): blocks sharing an A-tile == bm (mod 8) -> same XCD
// -> the f32 A-tile (512 KB) is re-read from that XCD's L2, not HBM.
__global__ __launch_bounds__(256) void k_gemm_score(
    const float* __restrict__ enc, const bf16_t* __restrict__ Bw,
    const float* __restrict__ bias, const float* __restrict__ v,
    float* __restrict__ scores) {
    __shared__ __attribute__((aligned(16))) bf16_t As[128 * 32];
    __shared__ __attribute__((aligned(16))) bf16_t Bs[128 * 32];

    const int tid = threadIdx.x;
    const int lane = tid & 63;
    const int wid = tid >> 6;
    const int wm = wid >> 1, wn = wid & 1;
    const int bm = blockIdx.x;   // 0..255 (M tiles) -- FAST dim for XCD affinity
    const int bn = blockIdx.y;   // 0..7   (N tiles)
    const int rsel = lane & 15, kg = lane >> 4;

    f32x4_t acc[4][4] = {};

    // A staging: thread -> (rows ar & 64+ar, k-quarter aq), 8 f32 each, cvt->bf16
    const int ar = tid >> 2;
    const int aq = tid & 3;
    const int asw = (tid >> 3) & 3;            // ((row>>1)&3) swizzle
    const size_t arow0 = (size_t)(bm * 128 + ar) * 1024;
    const size_t arow1 = (size_t)(bm * 128 + 64 + ar) * 1024;

    // B staging: wave stages chunks {wid*2, wid*2+1}; 16 rows x 64B per chunk
    const int c0 = wid * 2;
    const int bj = (lane & 3) ^ ((lane >> 3) & 3);  // swizzled source 16B-unit
    const bf16_t* bsrc0 = Bw + (size_t)(bn * 128 + c0 * 16 + (lane >> 2)) * 1024 + bj * 8;
    const bf16_t* bsrc1 = bsrc0 + (size_t)16 * 1024;

    for (int kt = 0; kt < 32; ++kt) {
        const int k0 = kt * 32;
        // --- B: async global->LDS (bf16, swizzled image) ---
        gld_lds16(bsrc0 + k0, Bs + c0 * 512);
        gld_lds16(bsrc1 + k0, Bs + (c0 + 1) * 512);
        // --- A: f32 load -> bf16 convert -> swizzled ds_write_b128 ---
        {
            const float* s0 = enc + arow0 + k0 + aq * 8;
            float4 f0 = *(const float4*)s0;
            float4 f1 = *(const float4*)(s0 + 4);
            bf16x8_t val;
            val[0] = (bf16_t)f0.x; val[1] = (bf16_t)f0.y; val[2] = (bf16_t)f0.z; val[3] = (bf16_t)f0.w;
            val[4] = (bf16_t)f1.x; val[5] = (bf16_t)f1.y; val[6] = (bf16_t)f1.z; val[7] = (bf16_t)f1.w;
            *(bf16x8_t*)(As + ar * 32 + (aq ^ asw) * 8) = val;
            const float* s1 = enc + arow1 + k0 + aq * 8;
            float4 g0 = *(const float4*)s1;
            float4 g1 = *(const float4*)(s1 + 4);
            bf16x8_t val2;
            val2[0] = (bf16_t)g0.x; val2[1] = (bf16_t)g0.y; val2[2] = (bf16_t)g0.z; val2[3] = (bf16_t)g0.w;
            val2[4] = (bf16_t)g1.x; val2[5] = (bf16_t)g1.y; val2[6] = (bf16_t)g1.z; val2[7] = (bf16_t)g1.w;
            *(bf16x8_t*)(As + (64 + ar) * 32 + (aq ^ asw) * 8) = val2;
        }
        __syncthreads();
        bf16x8_t af[4], bf[4];
        const int ksw = (kg ^ ((rsel >> 1) & 3)) * 8;
#pragma unroll
        for (int fm = 0; fm < 4; ++fm)
            af[fm] = *(const bf16x8_t*)(As + (wm * 64 + fm * 16 + rsel) * 32 + ksw);
#pragma unroll
        for (int fn = 0; fn < 4; ++fn)
            bf[fn] = *(const bf16x8_t*)(Bs + (wn * 64 + fn * 16 + rsel) * 32 + ksw);
#pragma unroll
        for (int fm = 0; fm < 4; ++fm)
#pragma unroll
            for (int fn = 0; fn < 4; ++fn)
                acc[fm][fn] = __builtin_amdgcn_mfma_f32_16x16x32_bf16(af[fm], bf[fn], acc[fm][fn], 0, 0, 0);
        __syncthreads();
    }

    // epilogue: energy = tanh(acc + bias[b][a]); scores[m] += energy * v[a]
    // C/D layout (m89-verified): row(M) = kg*4 + reg, col(N=a) = rsel
    const int b = bm >> 3;   // 128-row M-tiles lie within one batch
    float bias_l[4], v_l[4];
#pragma unroll
    for (int fn = 0; fn < 4; ++fn) {
        int a = bn * 128 + wn * 64 + fn * 16 + rsel;
        bias_l[fn] = bias[b * 1024 + a];
        v_l[fn] = v[a];
    }
    float part[16];
#pragma unroll
    for (int fm = 0; fm < 4; ++fm)
#pragma unroll
        for (int r = 0; r < 4; ++r) {
            float p = 0.0f;
#pragma unroll
            for (int fn = 0; fn < 4; ++fn) {
                float x = acc[fm][fn][r] + bias_l[fn];
                p += tanh_fast(x) * v_l[fn];
            }
            part[fm * 4 + r] = p;
        }
#pragma unroll
    for (int k = 0; k < 16; ++k) {
        part[k] += __shfl_xor(part[k], 1);
        part[k] += __shfl_xor(part[k], 2);
        part[k] += __shfl_xor(part[k], 4);
        part[k] += __shfl_xor(part[k], 8);
    }
    const int mrow0 = bm * 128 + wm * 64 + kg * 4;
#pragma unroll
    for (int k = 0; k < 16; ++k) {
        if (rsel == k) {
            int fm = k >> 2, r = k & 3;
            atomicAdd(&scores[mrow0 + fm * 16 + r], part[k]);
        }
    }
}

// ---------------------------------------------------------------------------
// K2 (fused softmax + context partials): block (chunk, b).
// Each block recomputes the row softmax stats from scores (8 KB read,
// deterministic), writes its 32-element alpha slice, then accumulates its
// chunk's context partial from f32 enc. No separate softmax dispatch.
__global__ void k_ctx(const float* __restrict__ enc, const float* __restrict__ scores,
                      const int* __restrict__ mask, float* __restrict__ alpha_out,
                      float* __restrict__ part) {
    __shared__ float red[4];
    __shared__ float red2[4];
    __shared__ float sal[1024];
    const int chunk = blockIdx.x;   // 0..31 (t-chunks of 32)
    const int b = blockIdx.y;       // 0..31
    const int t = threadIdx.x;

    float4 s = *(const float4*)(scores + b * 1024 + t * 4);
    int4 m = *(const int4*)(mask + b * 1024 + t * 4);
    float v0 = m.x ? s.x : NEG_BIG;
    float v1 = m.y ? s.y : NEG_BIG;
    float v2 = m.z ? s.z : NEG_BIG;
    float v3 = m.w ? s.w : NEG_BIG;
    float mx = fmaxf(fmaxf(v0, v1), fmaxf(v2, v3));
#pragma unroll
    for (int o = 1; o < 64; o <<= 1) mx = fmaxf(mx, __shfl_xor(mx, o));
    if ((t & 63) == 0) red[t >> 6] = mx;
    __syncthreads();
    mx = fmaxf(fmaxf(red[0], red[1]), fmaxf(red[2], red[3]));
    float e0 = m.x ? __expf(v0 - mx) : 0.0f;
    float e1 = m.y ? __expf(v1 - mx) : 0.0f;
    float e2 = m.z ? __expf(v2 - mx) : 0.0f;
    float e3 = m.w ? __expf(v3 - mx) : 0.0f;
    float sum = e0 + e1 + e2 + e3;
#pragma unroll
    for (int o = 1; o < 64; o <<= 1) sum += __shfl_xor(sum, o);
    if ((t & 63) == 0) red2[t >> 6] = sum;
    __syncthreads();
    float inv = 1.0f / (red2[0] + red2[1] + red2[2] + red2[3]);
    float4 al = {e0 * inv, e1 * inv, e2 * inv, e3 * inv};
    *(float4*)(sal + t * 4) = al;
    // this block owns alpha slice [chunk*32, chunk*32+32)
    if (t >= chunk * 8 && t < chunk * 8 + 8)
        *(float4*)(alpha_out + b * 1024 + t * 4) = al;
    __syncthreads();

    // context partial over this chunk's 32 timesteps
    const int e = t * 4;
    const float* ep = enc + ((size_t)b * 1024 + chunk * 32) * 1024 + e;
    const float* ap = sal + chunk * 32;
    float ax = 0.f, ay = 0.f, az = 0.f, aw = 0.f;
#pragma unroll 4
    for (int i = 0; i < 32; ++i) {
        float a = ap[i];
        float4 x = *(const float4*)(ep + (size_t)i * 1024);
        ax += a * x.x; ay += a * x.y; az += a * x.z; aw += a * x.w;
    }
    float4 o = {ax, ay, az, aw};
    *(float4*)(part + ((size_t)chunk * 32 + b) * 1024 + e) = o;
}

// K3: context[b][e] = sum over 32 partial chunks
__global__ void k_ctx_reduce(const float* __restrict__ part, float* __restrict__ ctx) {
    int b = blockIdx.x, t = threadIdx.x;
    int e = t * 4;
    float ax = 0.f, ay = 0.f, az = 0.f, aw = 0.f;
#pragma unroll 8
    for (int c = 0; c < 32; ++c) {
        float4 x = *(const float4*)(part + ((size_t)c * 32 + b) * 1024 + e);
        ax += x.x; ay += x.y; az += x.z; aw += x.w;
    }
    float4 o = {ax, ay, az, aw};
    *(float4*)(ctx + b * 1024 + e) = o;
}

// ---------------------------------------------------------------------------
extern "C" void kernel_launch(void* const* d_in, const int* in_sizes, int n_in,
                              void* d_out, int out_size, void* d_ws, size_t ws_size,
                              hipStream_t stream) {
    const float* dec  = (const float*)d_in[0];   // [32][1024]
    const float* enc  = (const float*)d_in[1];   // [32][1024][1024]
    const int*   mask = (const int*)d_in[2];     // [32][1024]
    const float* Ww   = (const float*)d_in[3];   // [1024][2048]
    const float* Wb   = (const float*)d_in[4];   // [1024]
    const float* vw   = (const float*)d_in[5];   // [1024]
    float* out = (float*)d_out;                  // [0:32768] context, [32768:65536] alpha

    char* ws = (char*)d_ws;
    bf16_t* Bw    = (bf16_t*)ws;                 //  2,097,152 B
    float*  bias  = (float*)(ws + 2097152);      //    131,072 B
    float*  score = (float*)(ws + 2228224);      //    131,072 B
    float*  part  = (float*)(ws + 2359296);      //  4,194,304 B (total ~6.3 MB)

    k_prep<<<1568, 256, 0, stream>>>(Ww, dec, Wb, Bw, bias, score);
    k_gemm_score<<<dim3(256, 8), 256, 0, stream>>>(enc, Bw, bias, vw, score);
    k_ctx<<<dim3(32, 32), 256, 0, stream>>>(enc, score, mask, out + 32768, part);
    k_ctx_reduce<<<32, 256, 0, stream>>>(part, out);
}

// Round 5
// 337.090 us; speedup vs baseline: 1.0531x; 1.0371x over previous
//
#include <hip/hip_runtime.h>
#include <hip/hip_bf16.h>

typedef __bf16 bf16_t;
typedef __bf16 bf16x8_t __attribute__((ext_vector_type(8)));
typedef float f32x4_t __attribute__((ext_vector_type(4)));

#define NEG_BIG -1000000000.0f

// async global->LDS, 16B per lane; LDS dest = wave-uniform base + lane*16
__device__ __forceinline__ void gld_lds16(const void* g, void* l) {
    __builtin_amdgcn_global_load_lds((const __attribute__((address_space(1))) void*)g,
                                     (__attribute__((address_space(3))) void*)l,
                                     16, 0, 0);
}

__device__ __forceinline__ float tanh_fast(float x) {
    float e = __expf(2.0f * x);
    return 1.0f - 2.0f / (e + 1.0f);
}

// ---------------------------------------------------------------------------
// K0 (prep-lite): blocks [0,512):    W_enc f32 -> bf16 (1M elems)
//                 blocks [512,1536): bias[b][a] = dec·W_dec[a] + W_b[a]
//                 blocks [1536,1568): zero scores (atomic accumulator)
__global__ void k_prep(const float* __restrict__ Ww, const float* __restrict__ dec,
                       const float* __restrict__ Wb, bf16_t* __restrict__ Bw,
                       float* __restrict__ bias, float* __restrict__ score) {
    const int bi = blockIdx.x;
    const int t = threadIdx.x;
    if (bi < 512) {
        size_t flat = (size_t)bi * 2048 + t * 8;   // over 1M W_enc elems
        int a = (int)(flat >> 10), e = (int)(flat & 1023);
        const float* src = Ww + (size_t)a * 2048 + 1024 + e;
        float4 f0 = *(const float4*)src;
        float4 f1 = *(const float4*)(src + 4);
        bf16x8_t v;
        v[0] = (bf16_t)f0.x; v[1] = (bf16_t)f0.y; v[2] = (bf16_t)f0.z; v[3] = (bf16_t)f0.w;
        v[4] = (bf16_t)f1.x; v[5] = (bf16_t)f1.y; v[6] = (bf16_t)f1.z; v[7] = (bf16_t)f1.w;
        *(bf16x8_t*)(Bw + flat) = v;
    } else if (bi < 1536) {
        __shared__ float wrow[1024];
        int a = bi - 512;
        *(float4*)(wrow + t * 4) = *(const float4*)(Ww + (size_t)a * 2048 + t * 4);
        __syncthreads();
        int b = t >> 3, j = t & 7;                // 32 batches x 8 threads
        const float* dp = dec + b * 1024 + j * 128;
        const float* wp = wrow + j * 128;
        float s = 0.0f;
#pragma unroll 8
        for (int i = 0; i < 128; i += 4) {
            float4 dv = *(const float4*)(dp + i);
            float4 wv = *(const float4*)(wp + i);
            s += dv.x * wv.x + dv.y * wv.y + dv.z * wv.z + dv.w * wv.w;
        }
        s += __shfl_xor(s, 1);
        s += __shfl_xor(s, 2);
        s += __shfl_xor(s, 4);
        if (j == 0) bias[b * 1024 + a] = s + Wb[a];
    } else {
        float4 z = {0.f, 0.f, 0.f, 0.f};
        *(float4*)(score + (size_t)(bi - 1536) * 1024 + t * 4) = z;
    }
}

// ---------------------------------------------------------------------------
// K1: enc_proj GEMM (bf16 MFMA; A = f32 enc converted in-register during
//     staging, B = bf16 W_enc via global_load_lds) + fused tanh + v-dot
//     -> atomicAdd scores[m]
// tile 128x128, BK=32, 256 threads = 4 waves (2x2), wave tile 64x64.
// Grid: 2048 linear blocks, decoded so the 8 blocks sharing an A-tile (same
// bm) are 8 CONSECUTIVE slots on ONE XCD (lin%8 fixed, lin/8 consecutive):
//   bm = (lin&7) + 8*(lin>>6),  bn = (lin>>3)&7
// -> inter-reuse working set = one 512 KB f32 A-tile << 4 MB L2, so 7/8 of
// A staging hits L2 (~200cyc drain) instead of HBM (~900cyc).
__global__ __launch_bounds__(256, 4) void k_gemm_score(
    const float* __restrict__ enc, const bf16_t* __restrict__ Bw,
    const float* __restrict__ bias, const float* __restrict__ v,
    float* __restrict__ scores) {
    __shared__ __attribute__((aligned(16))) bf16_t As[128 * 32];
    __shared__ __attribute__((aligned(16))) bf16_t Bs[128 * 32];

    const int tid = threadIdx.x;
    const int lane = tid & 63;
    const int wid = tid >> 6;
    const int wm = wid >> 1, wn = wid & 1;
    const int lin = blockIdx.x;
    const int bm = (lin & 7) + ((lin >> 6) << 3);  // 0..255 (M tiles)
    const int bn = (lin >> 3) & 7;                 // 0..7   (N tiles)
    const int rsel = lane & 15, kg = lane >> 4;

    f32x4_t acc[4][4] = {};

    // A staging: thread -> (rows ar & 64+ar, k-quarter aq), 8 f32 each, cvt->bf16
    const int ar = tid >> 2;
    const int aq = tid & 3;
    const int asw = (tid >> 3) & 3;            // ((row>>1)&3) swizzle
    const size_t arow0 = (size_t)(bm * 128 + ar) * 1024;
    const size_t arow1 = (size_t)(bm * 128 + 64 + ar) * 1024;

    // B staging: wave stages chunks {wid*2, wid*2+1}; 16 rows x 64B per chunk
    const int c0 = wid * 2;
    const int bj = (lane & 3) ^ ((lane >> 3) & 3);  // swizzled source 16B-unit
    const bf16_t* bsrc0 = Bw + (size_t)(bn * 128 + c0 * 16 + (lane >> 2)) * 1024 + bj * 8;
    const bf16_t* bsrc1 = bsrc0 + (size_t)16 * 1024;

    for (int kt = 0; kt < 32; ++kt) {
        const int k0 = kt * 32;
        // --- B: async global->LDS (bf16, swizzled image) ---
        gld_lds16(bsrc0 + k0, Bs + c0 * 512);
        gld_lds16(bsrc1 + k0, Bs + (c0 + 1) * 512);
        // --- A: f32 load -> bf16 convert -> swizzled ds_write_b128 ---
        {
            const float* s0 = enc + arow0 + k0 + aq * 8;
            float4 f0 = *(const float4*)s0;
            float4 f1 = *(const float4*)(s0 + 4);
            bf16x8_t val;
            val[0] = (bf16_t)f0.x; val[1] = (bf16_t)f0.y; val[2] = (bf16_t)f0.z; val[3] = (bf16_t)f0.w;
            val[4] = (bf16_t)f1.x; val[5] = (bf16_t)f1.y; val[6] = (bf16_t)f1.z; val[7] = (bf16_t)f1.w;
            *(bf16x8_t*)(As + ar * 32 + (aq ^ asw) * 8) = val;
            const float* s1 = enc + arow1 + k0 + aq * 8;
            float4 g0 = *(const float4*)s1;
            float4 g1 = *(const float4*)(s1 + 4);
            bf16x8_t val2;
            val2[0] = (bf16_t)g0.x; val2[1] = (bf16_t)g0.y; val2[2] = (bf16_t)g0.z; val2[3] = (bf16_t)g0.w;
            val2[4] = (bf16_t)g1.x; val2[5] = (bf16_t)g1.y; val2[6] = (bf16_t)g1.z; val2[7] = (bf16_t)g1.w;
            *(bf16x8_t*)(As + (64 + ar) * 32 + (aq ^ asw) * 8) = val2;
        }
        __syncthreads();
        bf16x8_t af[4], bf[4];
        const int ksw = (kg ^ ((rsel >> 1) & 3)) * 8;
#pragma unroll
        for (int fm = 0; fm < 4; ++fm)
            af[fm] = *(const bf16x8_t*)(As + (wm * 64 + fm * 16 + rsel) * 32 + ksw);
#pragma unroll
        for (int fn = 0; fn < 4; ++fn)
            bf[fn] = *(const bf16x8_t*)(Bs + (wn * 64 + fn * 16 + rsel) * 32 + ksw);
#pragma unroll
        for (int fm = 0; fm < 4; ++fm)
#pragma unroll
            for (int fn = 0; fn < 4; ++fn)
                acc[fm][fn] = __builtin_amdgcn_mfma_f32_16x16x32_bf16(af[fm], bf[fn], acc[fm][fn], 0, 0, 0);
        __syncthreads();
    }

    // epilogue: energy = tanh(acc + bias[b][a]); scores[m] += energy * v[a]
    // C/D layout (m89-verified): row(M) = kg*4 + reg, col(N=a) = rsel
    const int b = bm >> 3;   // 128-row M-tiles lie within one batch
    float bias_l[4], v_l[4];
#pragma unroll
    for (int fn = 0; fn < 4; ++fn) {
        int a = bn * 128 + wn * 64 + fn * 16 + rsel;
        bias_l[fn] = bias[b * 1024 + a];
        v_l[fn] = v[a];
    }
    float part[16];
#pragma unroll
    for (int fm = 0; fm < 4; ++fm)
#pragma unroll
        for (int r = 0; r < 4; ++r) {
            float p = 0.0f;
#pragma unroll
            for (int fn = 0; fn < 4; ++fn) {
                float x = acc[fm][fn][r] + bias_l[fn];
                p += tanh_fast(x) * v_l[fn];
            }
            part[fm * 4 + r] = p;
        }
#pragma unroll
    for (int k = 0; k < 16; ++k) {
        part[k] += __shfl_xor(part[k], 1);
        part[k] += __shfl_xor(part[k], 2);
        part[k] += __shfl_xor(part[k], 4);
        part[k] += __shfl_xor(part[k], 8);
    }
    const int mrow0 = bm * 128 + wm * 64 + kg * 4;
#pragma unroll
    for (int k = 0; k < 16; ++k) {
        if (rsel == k) {
            int fm = k >> 2, r = k & 3;
            atomicAdd(&scores[mrow0 + fm * 16 + r], part[k]);
        }
    }
}

// ---------------------------------------------------------------------------
// K2 (fused softmax + context partials): block (chunk, b).
// Each block recomputes the row softmax stats from scores (8 KB read,
// deterministic), writes its 32-element alpha slice, then accumulates its
// chunk's context partial from f32 enc.
__global__ void k_ctx(const float* __restrict__ enc, const float* __restrict__ scores,
                      const int* __restrict__ mask, float* __restrict__ alpha_out,
                      float* __restrict__ part) {
    __shared__ float red[4];
    __shared__ float red2[4];
    __shared__ float sal[1024];
    const int chunk = blockIdx.x;   // 0..31 (t-chunks of 32)
    const int b = blockIdx.y;       // 0..31
    const int t = threadIdx.x;

    float4 s = *(const float4*)(scores + b * 1024 + t * 4);
    int4 m = *(const int4*)(mask + b * 1024 + t * 4);
    float v0 = m.x ? s.x : NEG_BIG;
    float v1 = m.y ? s.y : NEG_BIG;
    float v2 = m.z ? s.z : NEG_BIG;
    float v3 = m.w ? s.w : NEG_BIG;
    float mx = fmaxf(fmaxf(v0, v1), fmaxf(v2, v3));
#pragma unroll
    for (int o = 1; o < 64; o <<= 1) mx = fmaxf(mx, __shfl_xor(mx, o));
    if ((t & 63) == 0) red[t >> 6] = mx;
    __syncthreads();
    mx = fmaxf(fmaxf(red[0], red[1]), fmaxf(red[2], red[3]));
    float e0 = m.x ? __expf(v0 - mx) : 0.0f;
    float e1 = m.y ? __expf(v1 - mx) : 0.0f;
    float e2 = m.z ? __expf(v2 - mx) : 0.0f;
    float e3 = m.w ? __expf(v3 - mx) : 0.0f;
    float sum = e0 + e1 + e2 + e3;
#pragma unroll
    for (int o = 1; o < 64; o <<= 1) sum += __shfl_xor(sum, o);
    if ((t & 63) == 0) red2[t >> 6] = sum;
    __syncthreads();
    float inv = 1.0f / (red2[0] + red2[1] + red2[2] + red2[3]);
    float4 al = {e0 * inv, e1 * inv, e2 * inv, e3 * inv};
    *(float4*)(sal + t * 4) = al;
    // this block owns alpha slice [chunk*32, chunk*32+32)
    if (t >= chunk * 8 && t < chunk * 8 + 8)
        *(float4*)(alpha_out + b * 1024 + t * 4) = al;
    __syncthreads();

    // context partial over this chunk's 32 timesteps
    const int e = t * 4;
    const float* ep = enc + ((size_t)b * 1024 + chunk * 32) * 1024 + e;
    const float* ap = sal + chunk * 32;
    float ax = 0.f, ay = 0.f, az = 0.f, aw = 0.f;
#pragma unroll 4
    for (int i = 0; i < 32; ++i) {
        float a = ap[i];
        float4 x = *(const float4*)(ep + (size_t)i * 1024);
        ax += a * x.x; ay += a * x.y; az += a * x.z; aw += a * x.w;
    }
    float4 o = {ax, ay, az, aw};
    *(float4*)(part + ((size_t)chunk * 32 + b) * 1024 + e) = o;
}

// K3: context[b][e] = sum over 32 partial chunks
__global__ void k_ctx_reduce(const float* __restrict__ part, float* __restrict__ ctx) {
    int b = blockIdx.x, t = threadIdx.x;
    int e = t * 4;
    float ax = 0.f, ay = 0.f, az = 0.f, aw = 0.f;
#pragma unroll 8
    for (int c = 0; c < 32; ++c) {
        float4 x = *(const float4*)(part + ((size_t)c * 32 + b) * 1024 + e);
        ax += x.x; ay += x.y; az += x.z; aw += x.w;
    }
    float4 o = {ax, ay, az, aw};
    *(float4*)(ctx + b * 1024 + e) = o;
}

// ---------------------------------------------------------------------------
extern "C" void kernel_launch(void* const* d_in, const int* in_sizes, int n_in,
                              void* d_out, int out_size, void* d_ws, size_t ws_size,
                              hipStream_t stream) {
    const float* dec  = (const float*)d_in[0];   // [32][1024]
    const float* enc  = (const float*)d_in[1];   // [32][1024][1024]
    const int*   mask = (const int*)d_in[2];     // [32][1024]
    const float* Ww   = (const float*)d_in[3];   // [1024][2048]
    const float* Wb   = (const float*)d_in[4];   // [1024]
    const float* vw   = (const float*)d_in[5];   // [1024]
    float* out = (float*)d_out;                  // [0:32768] context, [32768:65536] alpha

    char* ws = (char*)d_ws;
    bf16_t* Bw    = (bf16_t*)ws;                 //  2,097,152 B
    float*  bias  = (float*)(ws + 2097152);      //    131,072 B
    float*  score = (float*)(ws + 2228224);      //    131,072 B
    float*  part  = (float*)(ws + 2359296);      //  4,194,304 B (total ~6.3 MB)

    k_prep<<<1568, 256, 0, stream>>>(Ww, dec, Wb, Bw, bias, score);
    k_gemm_score<<<2048, 256, 0, stream>>>(enc, Bw, bias, vw, score);
    k_ctx<<<dim3(32, 32), 256, 0, stream>>>(enc, score, mask, out + 32768, part);
    k_ctx_reduce<<<32, 256, 0, stream>>>(part, out);
}